// Round 13
// baseline (183.177 us; speedup 1.0000x reference)
//
#include <hip/hip_runtime.h>

#define NUM_CODES 1296
#define DDIM 64
#define NUM_Q 131072      // 32*64*64
#define NTILE 81          // 1296 = 81 * 16, no tail
#define THREADS 256       // 4 waves
#define QPW 32            // queries per wave (2 MFMA row-fragments)
#define QPB 128           // queries per block; 1024 blocks
#define MARGIN 0.25f      // certified: 2*alpha <= 0.16 (bf16 screen), headroom
#define CAP 512           // per-wave candidate queue (expect ~50)

typedef __attribute__((ext_vector_type(8))) short bf16x8;
typedef __attribute__((ext_vector_type(4))) float f32x4;

__device__ __forceinline__ ushort f2bf(float f) {   // fp32 -> bf16 RNE
    unsigned u = __float_as_uint(f);
    return (ushort)((u + 0x7fffu + ((u >> 16) & 1u)) >> 16);
}

// enorm (exact numpy pairwise chain) + bf16 embeddings.
__global__ __launch_bounds__(64) void vq_prep(const float* __restrict__ emb,
                                              float* __restrict__ enorm,
                                              ushort* __restrict__ eh) {
    int k = blockIdx.x * 64 + threadIdx.x;
    if (k >= NUM_CODES) return;
    const float* e = emb + (size_t)k * DDIM;
    float f[DDIM];
#pragma unroll
    for (int i = 0; i < 16; ++i) {
        float4 v = *(const float4*)(e + 4 * i);
        f[4*i] = v.x; f[4*i+1] = v.y; f[4*i+2] = v.z; f[4*i+3] = v.w;
    }
    {
#pragma clang fp contract(off)
        float r8[8];
#pragma unroll
        for (int j = 0; j < 8; ++j) { float t = f[j] * f[j]; r8[j] = t; }
#pragma unroll
        for (int i = 1; i < 8; ++i) {
#pragma unroll
            for (int j = 0; j < 8; ++j) { float t = f[i*8+j] * f[i*8+j]; r8[j] += t; }
        }
        enorm[k] = ((r8[0]+r8[1])+(r8[2]+r8[3])) + ((r8[4]+r8[5])+(r8[6]+r8[7]));
    }
    uint* dh = (uint*)(eh + (size_t)k * DDIM);
#pragma unroll
    for (int i = 0; i < 32; ++i)
        dh[i] = (uint)f2bf(f[2*i]) | ((uint)f2bf(f[2*i+1]) << 16);
}

// ||x||^2 per query, exact numpy pairwise chain (for the rescore formula).
__global__ __launch_bounds__(256) void vq_xnorm(const float* __restrict__ x,
                                                float* __restrict__ xnorm) {
    int q = blockIdx.x * 256 + threadIdx.x;
    const float* r = x + (size_t)q * DDIM;
    float f[DDIM];
#pragma unroll
    for (int i = 0; i < 16; ++i) {
        float4 v = *(const float4*)(r + 4 * i);
        f[4*i] = v.x; f[4*i+1] = v.y; f[4*i+2] = v.z; f[4*i+3] = v.w;
    }
    {
#pragma clang fp contract(off)
        float r8[8];
#pragma unroll
        for (int j = 0; j < 8; ++j) { float t = f[j] * f[j]; r8[j] = t; }
#pragma unroll
        for (int i = 1; i < 8; ++i) {
#pragma unroll
            for (int j = 0; j < 8; ++j) { float t = f[i*8+j] * f[i*8+j]; r8[j] += t; }
        }
        xnorm[q] = ((r8[0]+r8[1])+(r8[2]+r8[3])) + ((r8[4]+r8[5])+(r8[6]+r8[7]));
    }
}

// bf16 MFMA screen (2 sweeps, depth-1 register prefetch) + exact fp32 rescore.
__global__ __launch_bounds__(THREADS) void vq_main(
        const float* __restrict__ x, const float* __restrict__ emb,
        const float* __restrict__ enorm_g, const float* __restrict__ xnorm,
        const ushort* __restrict__ eh, float* __restrict__ out) {
    __shared__ unsigned wq[4][CAP];                 // 8192 B
    __shared__ unsigned wcnt[4];
    __shared__ unsigned long long best64[4][QPW];   // 1024 B

    const int tid  = threadIdx.x;
    const int lane = tid & 63;
    const int w    = tid >> 6;
    const int cl   = lane & 15;          // MFMA col = code-in-tile
    const int g    = lane >> 4;          // k-slice / D-row group
    const long qw  = (long)blockIdx.x * QPB + w * QPW;

    if (lane < QPW) best64[w][lane] = ~0ULL;
    if (lane == 0) wcnt[w] = 0;
    __syncthreads();

    // A-frags (persistent): qset0 rows qw+cl, qset1 rows qw+16+cl; k = g*8(+32)
    bf16x8 a00, a01, a10, a11;
    {
        const float* xp0 = x + (qw + cl) * DDIM + g * 8;
        const float* xp1 = xp0 + 16 * DDIM;
#pragma unroll
        for (int j = 0; j < 8; ++j) {
            a00[j] = (short)f2bf(xp0[j]);
            a01[j] = (short)f2bf(xp0[j + 32]);
            a10[j] = (short)f2bf(xp1[j]);
            a11[j] = (short)f2bf(xp1[j + 32]);
        }
    }

    float rmin0[4], rmin1[4];
#pragma unroll
    for (int r = 0; r < 4; ++r) { rmin0[r] = __builtin_inff(); rmin1[r] = __builtin_inff(); }

    const ushort* ebase = eh + (size_t)cl * DDIM + g * 8;

    bf16x8 Ab0, Ab1, Bb0, Bb1;     // ping-pong prefetch buffers (named: stay in regs)
    float Ax2, Bx2;

#define LOADT(B0, B1, X2, CI) { \
        const ushort* ep_ = ebase + (size_t)(CI) * (16 * DDIM); \
        B0 = *(const bf16x8*)ep_; \
        B1 = *(const bf16x8*)(ep_ + 32); \
        X2 = enorm_g[(CI) * 16 + cl]; }

#define SCREEN(B0, B1, X2) { \
        f32x4 c0_ = {0.f,0.f,0.f,0.f}, c1_ = {0.f,0.f,0.f,0.f}; \
        c0_ = __builtin_amdgcn_mfma_f32_16x16x32_bf16(a00, B0, c0_, 0, 0, 0); \
        c1_ = __builtin_amdgcn_mfma_f32_16x16x32_bf16(a10, B0, c1_, 0, 0, 0); \
        c0_ = __builtin_amdgcn_mfma_f32_16x16x32_bf16(a01, B1, c0_, 0, 0, 0); \
        c1_ = __builtin_amdgcn_mfma_f32_16x16x32_bf16(a11, B1, c1_, 0, 0, 0); \
        _Pragma("unroll") \
        for (int r = 0; r < 4; ++r) { \
            rmin0[r] = fminf(rmin0[r], fmaf(-2.f, c0_[r], X2)); \
            rmin1[r] = fminf(rmin1[r], fmaf(-2.f, c1_[r], X2)); } }

    // ---- sweep 1: per-query screen minimum; loads one tile ahead ----
    LOADT(Ab0, Ab1, Ax2, 0);
    for (int p = 0; p < 40; ++p) {
        LOADT(Bb0, Bb1, Bx2, 2*p + 1);
        SCREEN(Ab0, Ab1, Ax2);
        LOADT(Ab0, Ab1, Ax2, 2*p + 2);
        SCREEN(Bb0, Bb1, Bx2);
    }
    SCREEN(Ab0, Ab1, Ax2);                          // tile 80

    // reduce over the 16 cols (codes); rows (queries) stay per-lane
#pragma unroll
    for (int m = 1; m < 16; m <<= 1) {
#pragma unroll
        for (int r = 0; r < 4; ++r) {
            rmin0[r] = fminf(rmin0[r], __shfl_xor(rmin0[r], m, 64));
            rmin1[r] = fminf(rmin1[r], __shfl_xor(rmin1[r], m, 64));
        }
    }
#pragma unroll
    for (int r = 0; r < 4; ++r) { rmin0[r] += MARGIN; rmin1[r] += MARGIN; }  // thresholds

#define ENQ(B0, B1, X2, CI) { \
        f32x4 c0_ = {0.f,0.f,0.f,0.f}, c1_ = {0.f,0.f,0.f,0.f}; \
        c0_ = __builtin_amdgcn_mfma_f32_16x16x32_bf16(a00, B0, c0_, 0, 0, 0); \
        c1_ = __builtin_amdgcn_mfma_f32_16x16x32_bf16(a10, B0, c1_, 0, 0, 0); \
        c0_ = __builtin_amdgcn_mfma_f32_16x16x32_bf16(a01, B1, c0_, 0, 0, 0); \
        c1_ = __builtin_amdgcn_mfma_f32_16x16x32_bf16(a11, B1, c1_, 0, 0, 0); \
        const int c_ = (CI) * 16 + cl; \
        _Pragma("unroll") \
        for (int r = 0; r < 4; ++r) { \
            float s0_ = fmaf(-2.f, c0_[r], X2); \
            float s1_ = fmaf(-2.f, c1_[r], X2); \
            if (s0_ <= rmin0[r]) { \
                unsigned i_ = atomicAdd(&wcnt[w], 1u); \
                if (i_ < CAP) wq[w][i_] = ((unsigned)(g*4 + r) << 11) | (unsigned)c_; } \
            if (s1_ <= rmin1[r]) { \
                unsigned i_ = atomicAdd(&wcnt[w], 1u); \
                if (i_ < CAP) wq[w][i_] = ((unsigned)(16 + g*4 + r) << 11) | (unsigned)c_; } } }

    // ---- sweep 2: identical recompute with prefetch, enqueue candidates ----
    LOADT(Ab0, Ab1, Ax2, 0);
    for (int p = 0; p < 40; ++p) {
        LOADT(Bb0, Bb1, Bx2, 2*p + 1);
        ENQ(Ab0, Ab1, Ax2, 2*p);
        LOADT(Ab0, Ab1, Ax2, 2*p + 2);
        ENQ(Bb0, Bb1, Bx2, 2*p + 1);
    }
    ENQ(Ab0, Ab1, Ax2, 80);
    __syncthreads();

    // ---- exact rescore (reference chain, bit-identical argmin) ----
    unsigned cnt = wcnt[w]; if (cnt > CAP) cnt = CAP;
    for (unsigned i = lane; i < cnt; i += 64) {
        unsigned p = wq[w][i];
        int ql = (int)(p >> 11); int c = (int)(p & 0x7FFu);
        long gq = qw + ql;
        const float* xr = x + gq * DDIM;
        const float* er = emb + (size_t)c * DDIM;
        float dot = 0.f;
#pragma unroll
        for (int p4 = 0; p4 < 16; ++p4) {
            float4 xv = *(const float4*)(xr + 4 * p4);
            float4 ev = *(const float4*)(er + 4 * p4);
            dot = fmaf(xv.x, ev.x, dot); dot = fmaf(xv.y, ev.y, dot);
            dot = fmaf(xv.z, ev.z, dot); dot = fmaf(xv.w, ev.w, dot);
        }
        float dist = (xnorm[gq] + enorm_g[c]) - 2.f * dot;   // reference rounding order
        unsigned u = __float_as_uint(dist);
        unsigned key = (u & 0x80000000u) ? ~u : (u | 0x80000000u);  // monotone map
        unsigned long long pk = ((unsigned long long)key << 32) | (unsigned)c;
        atomicMin(&best64[w][ql], pk);   // lexicographic (dist, c): ties -> low c
    }
    __syncthreads();

    // ---- outputs: codes (as float) + gathered embedding rows ----
#pragma unroll
    for (int qq = 0; qq < 8; ++qq) {
        int ql = qq * 4 + g;
        unsigned kk = (unsigned)(best64[w][ql] & 0xFFFFFFFFu);
        long gq = qw + ql;
        if (cl == 0) out[gq] = (float)kk;
        *(float4*)(out + (long)NUM_Q + gq * DDIM + cl * 4) =
            *(const float4*)(emb + (size_t)kk * DDIM + cl * 4);
    }
}

extern "C" void kernel_launch(void* const* d_in, const int* in_sizes, int n_in,
                              void* d_out, int out_size, void* d_ws, size_t ws_size,
                              hipStream_t stream) {
    const float* x   = (const float*)d_in[0];
    const float* emb = (const float*)d_in[1];
    float*  enorm = (float*)d_ws;                      // 5184 B (pad to 8192)
    float*  xnorm = (float*)((char*)d_ws + 8192);      // 524288 B
    ushort* eh    = (ushort*)((char*)d_ws + 532480);   // 165888 B (16B-aligned)

    hipLaunchKernelGGL(vq_prep, dim3((NUM_CODES + 63) / 64), dim3(64), 0, stream,
                       emb, enorm, eh);
    hipLaunchKernelGGL(vq_xnorm, dim3(NUM_Q / 256), dim3(256), 0, stream,
                       x, xnorm);
    hipLaunchKernelGGL(vq_main, dim3(NUM_Q / QPB), dim3(THREADS), 0, stream,
                       x, emb, enorm, xnorm, eh, (float*)d_out);
}

// Round 14
// 138.908 us; speedup vs baseline: 1.3187x; 1.3187x over previous
//
#include <hip/hip_runtime.h>

#define NUM_CODES 1296
#define PAD_CODES 1344    // 14 chunks * 96 (pads duplicate code 1295)
#define DDIM 64
#define NUM_Q 131072      // 32*64*64
#define THREADS 256       // 4 waves
#define QPW 32            // queries per wave
#define QPB 128           // queries per block; 1024 blocks
#define MARGIN 0.25f      // certified: 2*alpha <= 0.16 (bf16 screen) + headroom
#define CAP 512           // per-wave candidate queue (expect ~50)
#define CHUNK 96          // codes per LDS chunk (12288 B)
#define NSTEP 14          // PAD_CODES / CHUNK
#define TPC 6             // 16-code tiles per chunk

typedef __attribute__((ext_vector_type(8))) short bf16x8;
typedef __attribute__((ext_vector_type(4))) float f32x4;

__device__ __forceinline__ ushort f2bf(float f) {   // fp32 -> bf16 RNE
    unsigned u = __float_as_uint(f);
    return (ushort)((u + 0x7fffu + ((u >> 16) & 1u)) >> 16);
}

// enorm (exact numpy pairwise chain) + bf16 embeddings, slot-swizzled:
// 16B slot s (0..7) of code k stored at halfword k*64 + (s^(k&7))*8.
// Pads k>=NUM_CODES duplicate code 1295 (scores equal -> rmin unchanged).
__global__ __launch_bounds__(64) void vq_prep(const float* __restrict__ emb,
                                              float* __restrict__ enorm,
                                              ushort* __restrict__ eh) {
    int k = blockIdx.x * 64 + threadIdx.x;
    if (k >= PAD_CODES) return;
    int ks = k < NUM_CODES ? k : NUM_CODES - 1;
    const float* e = emb + (size_t)ks * DDIM;
    float f[DDIM];
#pragma unroll
    for (int i = 0; i < 16; ++i) {
        float4 v = *(const float4*)(e + 4 * i);
        f[4*i] = v.x; f[4*i+1] = v.y; f[4*i+2] = v.z; f[4*i+3] = v.w;
    }
    {
#pragma clang fp contract(off)
        float r8[8];
#pragma unroll
        for (int j = 0; j < 8; ++j) { float t = f[j] * f[j]; r8[j] = t; }
#pragma unroll
        for (int i = 1; i < 8; ++i) {
#pragma unroll
            for (int j = 0; j < 8; ++j) { float t = f[i*8+j] * f[i*8+j]; r8[j] += t; }
        }
        enorm[k] = ((r8[0]+r8[1])+(r8[2]+r8[3])) + ((r8[4]+r8[5])+(r8[6]+r8[7]));
    }
    ushort h[DDIM];
#pragma unroll
    for (int d = 0; d < DDIM; ++d) h[d] = f2bf(f[d]);
    uint* dh = (uint*)(eh + (size_t)k * DDIM);
#pragma unroll
    for (int s = 0; s < 8; ++s) {
        int ds = s ^ (k & 7);
#pragma unroll
        for (int j = 0; j < 4; ++j)
            dh[ds*4 + j] = (uint)h[s*8 + 2*j] | ((uint)h[s*8 + 2*j + 1] << 16);
    }
}

// ||x||^2 per query, exact numpy pairwise chain (for the rescore formula).
__global__ __launch_bounds__(256) void vq_xnorm(const float* __restrict__ x,
                                                float* __restrict__ xnorm) {
    int q = blockIdx.x * 256 + threadIdx.x;
    const float* r = x + (size_t)q * DDIM;
    float f[DDIM];
#pragma unroll
    for (int i = 0; i < 16; ++i) {
        float4 v = *(const float4*)(r + 4 * i);
        f[4*i] = v.x; f[4*i+1] = v.y; f[4*i+2] = v.z; f[4*i+3] = v.w;
    }
    {
#pragma clang fp contract(off)
        float r8[8];
#pragma unroll
        for (int j = 0; j < 8; ++j) { float t = f[j] * f[j]; r8[j] = t; }
#pragma unroll
        for (int i = 1; i < 8; ++i) {
#pragma unroll
            for (int j = 0; j < 8; ++j) { float t = f[i*8+j] * f[i*8+j]; r8[j] += t; }
        }
        xnorm[q] = ((r8[0]+r8[1])+(r8[2]+r8[3])) + ((r8[4]+r8[5])+(r8[6]+r8[7]));
    }
}

// LDS-staged bf16 MFMA screen (2 sweeps) + exact fp32 rescore.
__global__ __launch_bounds__(THREADS) void vq_main(
        const float* __restrict__ x, const float* __restrict__ emb,
        const float* __restrict__ enorm_g, const float* __restrict__ xnorm,
        const ushort* __restrict__ eh, float* __restrict__ out) {
    __shared__ ushort sbuf[2][CHUNK * DDIM];        // 2 x 12288 B
    __shared__ unsigned wq[4][CAP];                 // 8192 B
    __shared__ unsigned wcnt[4];
    __shared__ unsigned long long best64[4][QPW];   // 1024 B

    const int tid  = threadIdx.x;
    const int lane = tid & 63;
    const int w    = tid >> 6;
    const int cl   = lane & 15;          // MFMA col = code-in-tile
    const int g    = lane >> 4;          // k-slice / D-row group
    const long qw  = (long)blockIdx.x * QPB + w * QPW;

    if (lane < QPW) best64[w][lane] = ~0ULL;
    if (lane == 0) wcnt[w] = 0;

    // A-frags (persistent): rows qw+cl / qw+16+cl; k slices [g*8,+8) and +32
    bf16x8 a00, a01, a10, a11;
    {
        const float* xp0 = x + (qw + cl) * DDIM + g * 8;
        const float* xp1 = xp0 + 16 * DDIM;
#pragma unroll
        for (int j = 0; j < 8; ++j) {
            a00[j] = (short)f2bf(xp0[j]);
            a01[j] = (short)f2bf(xp0[j + 32]);
            a10[j] = (short)f2bf(xp1[j]);
            a11[j] = (short)f2bf(xp1[j + 32]);
        }
    }

    float rmin0[4], rmin1[4];
#pragma unroll
    for (int r = 0; r < 4; ++r) { rmin0[r] = __builtin_inff(); rmin1[r] = __builtin_inff(); }

    const int slot0 = (g     ^ (cl & 7)) * 8;   // swizzled halfword offsets
    const int slot1 = ((g+4) ^ (cl & 7)) * 8;

    // ================= SWEEP 1: per-query screen minimum =================
    {   // prologue: stage chunk 0
        const float4* src = (const float4*)eh;
        float4 s0 = src[tid], s1 = src[256 + tid], s2 = src[512 + tid];
        *(float4*)&sbuf[0][(size_t)tid * 8]         = s0;
        *(float4*)&sbuf[0][(size_t)(256 + tid) * 8] = s1;
        *(float4*)&sbuf[0][(size_t)(512 + tid) * 8] = s2;
    }
    __syncthreads();
    int cur = 0;
    for (int s = 0; s < NSTEP; ++s) {
        float4 n0, n1, n2;
        const bool more = (s + 1 < NSTEP);
        if (more) {   // issue-early: next chunk global loads
            const float4* src = (const float4*)(eh + (size_t)(s + 1) * CHUNK * DDIM);
            n0 = src[tid]; n1 = src[256 + tid]; n2 = src[512 + tid];
        }
        const int cb = s * CHUNK;
        float en[TPC];
#pragma unroll
        for (int t = 0; t < TPC; ++t) en[t] = enorm_g[cb + t * 16 + cl];
#pragma unroll
        for (int t = 0; t < TPC; ++t) {
            const ushort* bp = &sbuf[cur][(size_t)(t * 16 + cl) * DDIM];
            bf16x8 b0 = *(const bf16x8*)(bp + slot0);
            bf16x8 b1 = *(const bf16x8*)(bp + slot1);
            f32x4 c00 = {0,0,0,0}, c01 = {0,0,0,0}, c10 = {0,0,0,0}, c11 = {0,0,0,0};
            c00 = __builtin_amdgcn_mfma_f32_16x16x32_bf16(a00, b0, c00, 0, 0, 0);
            c10 = __builtin_amdgcn_mfma_f32_16x16x32_bf16(a10, b0, c10, 0, 0, 0);
            c01 = __builtin_amdgcn_mfma_f32_16x16x32_bf16(a01, b1, c01, 0, 0, 0);
            c11 = __builtin_amdgcn_mfma_f32_16x16x32_bf16(a11, b1, c11, 0, 0, 0);
#pragma unroll
            for (int r = 0; r < 4; ++r) {
                rmin0[r] = fminf(rmin0[r], fmaf(-2.f, c00[r] + c01[r], en[t]));
                rmin1[r] = fminf(rmin1[r], fmaf(-2.f, c10[r] + c11[r], en[t]));
            }
        }
        if (more) {   // write-late into the other buffer
            *(float4*)&sbuf[cur ^ 1][(size_t)tid * 8]         = n0;
            *(float4*)&sbuf[cur ^ 1][(size_t)(256 + tid) * 8] = n1;
            *(float4*)&sbuf[cur ^ 1][(size_t)(512 + tid) * 8] = n2;
        }
        __syncthreads();
        cur ^= 1;
    }

    // reduce over the 16 cols (codes); rows (queries) stay per-lane
#pragma unroll
    for (int m = 1; m < 16; m <<= 1) {
#pragma unroll
        for (int r = 0; r < 4; ++r) {
            rmin0[r] = fminf(rmin0[r], __shfl_xor(rmin0[r], m, 64));
            rmin1[r] = fminf(rmin1[r], __shfl_xor(rmin1[r], m, 64));
        }
    }
#pragma unroll
    for (int r = 0; r < 4; ++r) { rmin0[r] += MARGIN; rmin1[r] += MARGIN; }

    // ================= SWEEP 2: recompute, enqueue candidates =================
    {
        const float4* src = (const float4*)eh;
        float4 s0 = src[tid], s1 = src[256 + tid], s2 = src[512 + tid];
        *(float4*)&sbuf[cur][(size_t)tid * 8]         = s0;
        *(float4*)&sbuf[cur][(size_t)(256 + tid) * 8] = s1;
        *(float4*)&sbuf[cur][(size_t)(512 + tid) * 8] = s2;
    }
    __syncthreads();
    for (int s = 0; s < NSTEP; ++s) {
        float4 n0, n1, n2;
        const bool more = (s + 1 < NSTEP);
        if (more) {
            const float4* src = (const float4*)(eh + (size_t)(s + 1) * CHUNK * DDIM);
            n0 = src[tid]; n1 = src[256 + tid]; n2 = src[512 + tid];
        }
        const int cb = s * CHUNK;
        float en[TPC];
#pragma unroll
        for (int t = 0; t < TPC; ++t) en[t] = enorm_g[cb + t * 16 + cl];
#pragma unroll
        for (int t = 0; t < TPC; ++t) {
            const ushort* bp = &sbuf[cur][(size_t)(t * 16 + cl) * DDIM];
            bf16x8 b0 = *(const bf16x8*)(bp + slot0);
            bf16x8 b1 = *(const bf16x8*)(bp + slot1);
            f32x4 c00 = {0,0,0,0}, c01 = {0,0,0,0}, c10 = {0,0,0,0}, c11 = {0,0,0,0};
            c00 = __builtin_amdgcn_mfma_f32_16x16x32_bf16(a00, b0, c00, 0, 0, 0);
            c10 = __builtin_amdgcn_mfma_f32_16x16x32_bf16(a10, b0, c10, 0, 0, 0);
            c01 = __builtin_amdgcn_mfma_f32_16x16x32_bf16(a01, b1, c01, 0, 0, 0);
            c11 = __builtin_amdgcn_mfma_f32_16x16x32_bf16(a11, b1, c11, 0, 0, 0);
            const int c_ = cb + t * 16 + cl;
#pragma unroll
            for (int r = 0; r < 4; ++r) {
                float s0_ = fmaf(-2.f, c00[r] + c01[r], en[t]);
                float s1_ = fmaf(-2.f, c10[r] + c11[r], en[t]);
                if (c_ < NUM_CODES && s0_ <= rmin0[r]) {
                    unsigned i_ = atomicAdd(&wcnt[w], 1u);
                    if (i_ < CAP) wq[w][i_] = ((unsigned)(g*4 + r) << 11) | (unsigned)c_;
                }
                if (c_ < NUM_CODES && s1_ <= rmin1[r]) {
                    unsigned i_ = atomicAdd(&wcnt[w], 1u);
                    if (i_ < CAP) wq[w][i_] = ((unsigned)(16 + g*4 + r) << 11) | (unsigned)c_;
                }
            }
        }
        if (more) {
            *(float4*)&sbuf[cur ^ 1][(size_t)tid * 8]         = n0;
            *(float4*)&sbuf[cur ^ 1][(size_t)(256 + tid) * 8] = n1;
            *(float4*)&sbuf[cur ^ 1][(size_t)(512 + tid) * 8] = n2;
        }
        __syncthreads();
        cur ^= 1;
    }

    // ---- exact rescore (reference chain, bit-identical argmin) ----
    unsigned cnt = wcnt[w]; if (cnt > CAP) cnt = CAP;
    for (unsigned i = lane; i < cnt; i += 64) {
        unsigned p = wq[w][i];
        int ql = (int)(p >> 11); int c = (int)(p & 0x7FFu);
        long gq = qw + ql;
        const float* xr = x + gq * DDIM;
        const float* er = emb + (size_t)c * DDIM;
        float dot = 0.f;
#pragma unroll
        for (int p4 = 0; p4 < 16; ++p4) {
            float4 xv = *(const float4*)(xr + 4 * p4);
            float4 ev = *(const float4*)(er + 4 * p4);
            dot = fmaf(xv.x, ev.x, dot); dot = fmaf(xv.y, ev.y, dot);
            dot = fmaf(xv.z, ev.z, dot); dot = fmaf(xv.w, ev.w, dot);
        }
        float dist = (xnorm[gq] + enorm_g[c]) - 2.f * dot;   // reference rounding order
        unsigned u = __float_as_uint(dist);
        unsigned key = (u & 0x80000000u) ? ~u : (u | 0x80000000u);  // monotone map
        unsigned long long pk = ((unsigned long long)key << 32) | (unsigned)c;
        atomicMin(&best64[w][ql], pk);   // lexicographic (dist, c): ties -> low c
    }
    __syncthreads();

    // ---- outputs: codes (as float) + gathered embedding rows ----
#pragma unroll
    for (int qq = 0; qq < 8; ++qq) {
        int ql = qq * 4 + g;
        unsigned kk = (unsigned)(best64[w][ql] & 0xFFFFFFFFu);
        long gq = qw + ql;
        if (cl == 0) out[gq] = (float)kk;
        *(float4*)(out + (long)NUM_Q + gq * DDIM + cl * 4) =
            *(const float4*)(emb + (size_t)kk * DDIM + cl * 4);
    }
}

extern "C" void kernel_launch(void* const* d_in, const int* in_sizes, int n_in,
                              void* d_out, int out_size, void* d_ws, size_t ws_size,
                              hipStream_t stream) {
    const float* x   = (const float*)d_in[0];
    const float* emb = (const float*)d_in[1];
    float*  enorm = (float*)d_ws;                      // 5376 B (pad to 8192)
    float*  xnorm = (float*)((char*)d_ws + 8192);      // 524288 B
    ushort* eh    = (ushort*)((char*)d_ws + 532480);   // 172032 B (16B-aligned)

    hipLaunchKernelGGL(vq_prep, dim3(PAD_CODES / 64), dim3(64), 0, stream,
                       emb, enorm, eh);
    hipLaunchKernelGGL(vq_xnorm, dim3(NUM_Q / 256), dim3(256), 0, stream,
                       x, xnorm);
    hipLaunchKernelGGL(vq_main, dim3(NUM_Q / QPB), dim3(THREADS), 0, stream,
                       x, emb, enorm, xnorm, eh, (float*)d_out);
}